// Round 1
// baseline (227.884 us; speedup 1.0000x reference)
//
#include <hip/hip_runtime.h>

// CRF forward (log-partition) — B=1024, T=512, K=64.
// One wave (64 lanes) per batch element. Lane i owns output tag i:
//   - E[i][j] = exp(trans[i][j]) held in 64 VGPRs (full unroll -> registers)
//   - per step: c = fv[lane0]; w = exp(fv - c) written to LDS;
//     s[i] = sum_j E[i][j] * w[j] (uniform-address float4 LDS broadcast reads);
//     fv[i] = emit[i] + c + log(s[i])
// Only the final LSE at t = seq_len-1 is needed.

constexpr int CRF_B = 1024;
constexpr int CRF_T = 512;
constexpr int CRF_K = 64;

__global__ __launch_bounds__(64) void crf_forward_kernel(
    const float* __restrict__ feats,      // [B, T, K]
    const float* __restrict__ trans,      // [K, K]
    const int*   __restrict__ seq_lens,   // [B]
    float*       __restrict__ out)        // [B]
{
    const int b    = blockIdx.x;
    const int lane = threadIdx.x;

    __shared__ __align__(16) float wbuf[2][CRF_K];

    // Precompute exp(trans[lane][:]) into registers (statically indexed).
    float E[CRF_K];
    {
        const float* trow = trans + lane * CRF_K;
#pragma unroll
        for (int j = 0; j < CRF_K; ++j) E[j] = __expf(trow[j]);
    }

    const int L = seq_lens[b];                       // uniform across the wave
    const float* fb = feats + (size_t)b * CRF_T * CRF_K + lane;

    float fv = fb[0];                                // t = 0: emissions
    float emit_next = (L > 1) ? fb[CRF_K] : 0.0f;    // prefetch t = 1

    int p = 0;
    for (int t = 1; t < L; ++t) {
        const float emit = emit_next;
        if (t + 1 < L) emit_next = fb[(size_t)(t + 1) * CRF_K];  // prefetch

        const float c = __shfl(fv, 0, 64);           // cheap stability offset
        const float w = __expf(fv - c);
        wbuf[p][lane] = w;
        __syncthreads();                             // LDS visibility (1-wave block)

        float a0 = 0.f, a1 = 0.f, a2 = 0.f, a3 = 0.f;
#pragma unroll
        for (int j = 0; j < CRF_K; j += 4) {
            const float4 w4 = *(const float4*)&wbuf[p][j];   // uniform broadcast read
            a0 = fmaf(E[j + 0], w4.x, a0);
            a1 = fmaf(E[j + 1], w4.y, a1);
            a2 = fmaf(E[j + 2], w4.z, a2);
            a3 = fmaf(E[j + 3], w4.w, a3);
        }
        const float s = (a0 + a1) + (a2 + a3);
        fv = emit + c + __logf(s);
        p ^= 1;                                      // double buffer -> 1 barrier/step
    }

    // Final LSE over the 64 lanes (only alpha we actually need).
    const float c = __shfl(fv, 0, 64);
    float e = __expf(fv - c);
#pragma unroll
    for (int off = 32; off > 0; off >>= 1) e += __shfl_xor(e, off, 64);
    if (lane == 0) out[b] = c + __logf(e);
}

extern "C" void kernel_launch(void* const* d_in, const int* in_sizes, int n_in,
                              void* d_out, int out_size, void* d_ws, size_t ws_size,
                              hipStream_t stream)
{
    const float* feats    = (const float*)d_in[0];
    const float* trans    = (const float*)d_in[1];
    const int*   seq_lens = (const int*)d_in[2];
    float*       out      = (float*)d_out;

    crf_forward_kernel<<<dim3(CRF_B), dim3(CRF_K), 0, stream>>>(
        feats, trans, seq_lens, out);
}

// Round 2
// 157.704 us; speedup vs baseline: 1.4450x; 1.4450x over previous
//
#include <hip/hip_runtime.h>

// CRF forward (log-partition) — B=1024, T=512, K=64.
// One wave per batch element; lane i owns tag i; E[i][:] = exp(trans[i][:])
// in 64 VGPRs. Per step the w[j] broadcast is done with v_readlane_b32
// (immediate lane) -> SGPR -> scalar operand of v_fma_f32: no LDS, no
// barrier, so the emission prefetch is never drained by a barrier waitcnt.

constexpr int CRF_B = 1024;
constexpr int CRF_T = 512;
constexpr int CRF_K = 64;

__device__ __forceinline__ float bcast_lane(float v, int lane) {
    return __int_as_float(__builtin_amdgcn_readlane(__float_as_int(v), lane));
}

__global__ __launch_bounds__(64) void crf_forward_kernel(
    const float* __restrict__ feats,      // [B, T, K]
    const float* __restrict__ trans,      // [K, K]
    const int*   __restrict__ seq_lens,   // [B]
    float*       __restrict__ out)        // [B]
{
    const int b    = blockIdx.x;
    const int lane = threadIdx.x;

    // E[j] = exp(trans[lane][j]) — statically indexed -> stays in VGPRs.
    float E[CRF_K];
    {
        const float* trow = trans + lane * CRF_K;
#pragma unroll
        for (int j = 0; j < CRF_K; j += 4) {
            const float4 t4 = *(const float4*)&trow[j];
            E[j + 0] = __expf(t4.x);
            E[j + 1] = __expf(t4.y);
            E[j + 2] = __expf(t4.z);
            E[j + 3] = __expf(t4.w);
        }
    }

    const int L    = seq_lens[b];            // uniform across the wave
    const int Lm1  = L - 1;
    const float* fb = feats + (size_t)b * CRF_T * CRF_K + lane;

    float fv = fb[0];                        // t = 0: emissions only

    // Depth-3 emission prefetch pipeline (covers HBM latency; no barriers
    // anywhere, so these loads stay in flight across steps).
    float e1 = fb[min(1, Lm1) * CRF_K];
    float e2 = fb[min(2, Lm1) * CRF_K];
    float e3 = fb[min(3, Lm1) * CRF_K];

    for (int t = 1; t < L; ++t) {
        const float emit = e1;
        e1 = e2;
        e2 = e3;
        e3 = fb[min(t + 3, Lm1) * CRF_K];    // clamped: dup loads, unused

        const float c = bcast_lane(fv, 0);   // cheap stability offset
        const float w = __expf(fv - c);

        float a0 = 0.f, a1 = 0.f, a2 = 0.f, a3 = 0.f;
#pragma unroll
        for (int j = 0; j < CRF_K; j += 4) {
            a0 = fmaf(E[j + 0], bcast_lane(w, j + 0), a0);
            a1 = fmaf(E[j + 1], bcast_lane(w, j + 1), a1);
            a2 = fmaf(E[j + 2], bcast_lane(w, j + 2), a2);
            a3 = fmaf(E[j + 3], bcast_lane(w, j + 3), a3);
        }
        fv = emit + c + __logf((a0 + a1) + (a2 + a3));
    }

    // Final LSE across the 64 lanes (the only alpha we need).
    const float c = bcast_lane(fv, 0);
    float e = __expf(fv - c);
#pragma unroll
    for (int off = 32; off > 0; off >>= 1) e += __shfl_xor(e, off, 64);
    if (lane == 0) out[b] = c + __logf(e);
}

extern "C" void kernel_launch(void* const* d_in, const int* in_sizes, int n_in,
                              void* d_out, int out_size, void* d_ws, size_t ws_size,
                              hipStream_t stream)
{
    const float* feats    = (const float*)d_in[0];
    const float* trans    = (const float*)d_in[1];
    const int*   seq_lens = (const int*)d_in[2];
    float*       out      = (float*)d_out;

    crf_forward_kernel<<<dim3(CRF_B), dim3(CRF_K), 0, stream>>>(
        feats, trans, seq_lens, out);
}